// Round 2
// baseline (452.475 us; speedup 1.0000x reference)
//
#include <hip/hip_runtime.h>
#include <hip/hip_bf16.h>
#include <cstdint>

typedef __hip_bfloat16 bf16;
typedef short short8 __attribute__((ext_vector_type(8)));
typedef float f32x4 __attribute__((ext_vector_type(4)));

#define AS1C(p) ((const __attribute__((address_space(1))) void*)(p))
#define AS3(p)  ((__attribute__((address_space(3))) void*)(p))

// ---------------------------------------------------------------------------
// fp32 -> bf16 conversion (vectorized, memory-bound)
// ---------------------------------------------------------------------------
__global__ void cvt_f32_bf16(const float* __restrict__ src, bf16* __restrict__ dst, int n4)
{
    int i = blockIdx.x * blockDim.x + threadIdx.x;
    if (i >= n4) return;
    float4 v = ((const float4*)src)[i];
    __align__(8) bf16 t[4] = { __float2bfloat16(v.x), __float2bfloat16(v.y),
                               __float2bfloat16(v.z), __float2bfloat16(v.w) };
    ((uint2*)dst)[i] = *(const uint2*)t;
}

// ---------------------------------------------------------------------------
// C[M,N] = A[M,K] @ B[N,K]^T (+ bias[n]). A,B bf16 (A has row stride lda),
// fp32 accumulate, output OUT_T (bf16 or float). m97 structure: 128x128 tile,
// BK=32, 4 waves 2x2, 16x16x32 bf16 MFMA, global_load_lds width=16.
// ---------------------------------------------------------------------------
template<bool HAS_BIAS, typename OUT_T>
__global__ __launch_bounds__(256, 2)
void gemm_bt(const bf16* __restrict__ A, int lda, const bf16* __restrict__ B,
             const float* __restrict__ bias, OUT_T* __restrict__ C,
             int M, int N, int K)
{
    __shared__ __align__(16) bf16 As[128 * 32];
    __shared__ __align__(16) bf16 Bs[128 * 32];
    const int tid  = threadIdx.x;
    const int wave = tid >> 6, lane = tid & 63;
    const int wm = wave >> 1, wn = wave & 1;
    const int quad = lane >> 4, l15 = lane & 15;
    const int tile_m = blockIdx.y, tile_n = blockIdx.x;

    const bf16* Ap = A + (size_t)tile_m * 128 * lda;
    const bf16* Bp = B + (size_t)tile_n * 128 * K;

    const int srow = lane >> 2;        // 0..15 row within a 16-row chunk
    const int scol = (lane & 3) * 8;   // 0,8,16,24

    f32x4 acc[4][4];
    #pragma unroll
    for (int i = 0; i < 4; i++)
        #pragma unroll
        for (int j = 0; j < 4; j++) acc[i][j] = (f32x4){0.f, 0.f, 0.f, 0.f};

    for (int k0 = 0; k0 < K; k0 += 32) {
        #pragma unroll
        for (int cc = 0; cc < 2; cc++) {
            int c = wave + cc * 4;                 // chunk 0..7 = rows c*16..+15
            const bf16* ga = Ap + (size_t)(c * 16 + srow) * lda + k0 + scol;
            __builtin_amdgcn_global_load_lds(AS1C(ga), AS3(&As[c * 16 * 32]), 16, 0, 0);
            const bf16* gb = Bp + (size_t)(c * 16 + srow) * K + k0 + scol;
            __builtin_amdgcn_global_load_lds(AS1C(gb), AS3(&Bs[c * 16 * 32]), 16, 0, 0);
        }
        __syncthreads();

        short8 af[4], bfr[4];
        #pragma unroll
        for (int mi = 0; mi < 4; mi++)
            af[mi] = *(const short8*)&As[(wm * 64 + mi * 16 + l15) * 32 + quad * 8];
        #pragma unroll
        for (int ni = 0; ni < 4; ni++)
            bfr[ni] = *(const short8*)&Bs[(wn * 64 + ni * 16 + l15) * 32 + quad * 8];
        #pragma unroll
        for (int mi = 0; mi < 4; mi++)
            #pragma unroll
            for (int ni = 0; ni < 4; ni++)
                acc[mi][ni] = __builtin_amdgcn_mfma_f32_16x16x32_bf16(
                    af[mi], bfr[ni], acc[mi][ni], 0, 0, 0);
        __syncthreads();
    }

    // epilogue: C/D layout row = quad*4+r, col = l15 (m89/m91-verified)
    #pragma unroll
    for (int mi = 0; mi < 4; mi++) {
        #pragma unroll
        for (int ni = 0; ni < 4; ni++) {
            int col = tile_n * 128 + wn * 64 + ni * 16 + l15;
            float bv = HAS_BIAS ? bias[col] : 0.f;
            #pragma unroll
            for (int r = 0; r < 4; r++) {
                int row = tile_m * 128 + wm * 64 + mi * 16 + quad * 4 + r;
                float v = acc[mi][ni][r] + bv;
                if constexpr (__is_same(OUT_T, float))
                    C[(size_t)row * N + col] = v;
                else
                    C[(size_t)row * N + col] = __float2bfloat16(v);
            }
        }
    }
}

// ---------------------------------------------------------------------------
// Causal flash attention. qkv: [8192, 3072] bf16 (q|k|v, each 1024 = 16h x 64).
// One block per (q-tile 64, head, batch); 4 waves, wave w owns q-rows w*16..+15.
// Online softmax fp32; P -> LDS -> A-frag round trip (m120 pattern).
// Output written back into the q-columns of qkv (stride 3072): each block
// writes exactly the q-stripe only it reads (and reads it before writing).
// ---------------------------------------------------------------------------
__global__ __launch_bounds__(256, 2)
void flash_attn(bf16* __restrict__ qkv)
{
    const int qt = blockIdx.x;   // 0..31
    const int h  = blockIdx.y;   // 0..15
    const int b  = blockIdx.z;   // 0..3
    const int tid  = threadIdx.x;
    const int wave = tid >> 6, lane = tid & 63;
    const int quad = lane >> 4, l15 = lane & 15;

    __shared__ __align__(16) bf16 Qs[64][72];
    __shared__ __align__(16) bf16 Ks[64][72];
    __shared__ __align__(16) bf16 Vt[64][72];       // V transposed: Vt[d][kc]
    __shared__ __align__(16) bf16 Ps[4][16][72];    // per-wave P tile

    const int r  = tid >> 2;         // staging row 0..63
    const int c0 = (tid & 3) * 16;   // staging col 0,16,32,48
    const int q0 = qt * 64;
    const size_t rs = 3072;

    // stage Q tile once
    {
        const bf16* qg = qkv + (size_t)(b * 2048 + q0 + r) * rs + h * 64 + c0;
        uint4 v0 = *(const uint4*)qg;
        uint4 v1 = *(const uint4*)(qg + 8);
        *(uint4*)&Qs[r][c0]     = v0;
        *(uint4*)&Qs[r][c0 + 8] = v1;
    }
    __syncthreads();

    short8 qa[2];   // A-frag: m = l15, k = quad*8+j within each 32-wide window
    #pragma unroll
    for (int ks = 0; ks < 2; ks++)
        qa[ks] = *(const short8*)&Qs[wave * 16 + l15][ks * 32 + quad * 8];

    f32x4 o[4];
    #pragma unroll
    for (int nt = 0; nt < 4; nt++) o[nt] = (f32x4){0.f, 0.f, 0.f, 0.f};
    float m_prev[4], lsum[4];
    #pragma unroll
    for (int rr = 0; rr < 4; rr++) { m_prev[rr] = -INFINITY; lsum[rr] = 0.f; }

    for (int j = 0; j <= qt; j++) {
        // stage K (natural) and V (transposed)
        {
            const bf16* kg = qkv + (size_t)(b * 2048 + j * 64 + r) * rs + 1024 + h * 64 + c0;
            uint4 k0v = *(const uint4*)kg;
            uint4 k1v = *(const uint4*)(kg + 8);
            *(uint4*)&Ks[r][c0]     = k0v;
            *(uint4*)&Ks[r][c0 + 8] = k1v;
            const bf16* vg = kg + 1024;
            uint4 v0 = *(const uint4*)vg;
            uint4 v1 = *(const uint4*)(vg + 8);
            __align__(16) bf16 tmp[16];
            *(uint4*)&tmp[0] = v0;
            *(uint4*)&tmp[8] = v1;
            #pragma unroll
            for (int i = 0; i < 16; i++) Vt[c0 + i][r] = tmp[i];
        }
        __syncthreads();

        // S = Q K^T : 4 col-tiles of 16, 2 k-steps each
        f32x4 s[4];
        #pragma unroll
        for (int tc = 0; tc < 4; tc++) {
            short8 kb0 = *(const short8*)&Ks[tc * 16 + l15][quad * 8];
            short8 kb1 = *(const short8*)&Ks[tc * 16 + l15][32 + quad * 8];
            f32x4 z = (f32x4){0.f, 0.f, 0.f, 0.f};
            z = __builtin_amdgcn_mfma_f32_16x16x32_bf16(qa[0], kb0, z, 0, 0, 0);
            z = __builtin_amdgcn_mfma_f32_16x16x32_bf16(qa[1], kb1, z, 0, 0, 0);
            s[tc] = z;
        }
        // scale + causal mask (only the diagonal tile j==qt needs masking)
        #pragma unroll
        for (int tc = 0; tc < 4; tc++)
            #pragma unroll
            for (int rr = 0; rr < 4; rr++) {
                float v = s[tc][rr] * 0.125f;   // Hd^-0.5 = 1/8
                if (j == qt && (tc * 16 + l15) > (wave * 16 + quad * 4 + rr))
                    v = -INFINITY;
                s[tc][rr] = v;
            }
        // online softmax row stats: shfl over the 16 lanes of this quad-row
        float mnew[4], alpha[4];
        #pragma unroll
        for (int rr = 0; rr < 4; rr++) {
            float mr = fmaxf(fmaxf(s[0][rr], s[1][rr]), fmaxf(s[2][rr], s[3][rr]));
            #pragma unroll
            for (int sh = 1; sh < 16; sh <<= 1)
                mr = fmaxf(mr, __shfl_xor(mr, sh));
            mnew[rr]  = fmaxf(m_prev[rr], mr);
            alpha[rr] = __expf(m_prev[rr] - mnew[rr]);
            m_prev[rr] = mnew[rr];
        }
        #pragma unroll
        for (int tc = 0; tc < 4; tc++)
            #pragma unroll
            for (int rr = 0; rr < 4; rr++)
                s[tc][rr] = __expf(s[tc][rr] - mnew[rr]);
        #pragma unroll
        for (int rr = 0; rr < 4; rr++) {
            float rsum = s[0][rr] + s[1][rr] + s[2][rr] + s[3][rr];
            #pragma unroll
            for (int sh = 1; sh < 16; sh <<= 1)
                rsum += __shfl_xor(rsum, sh);
            lsum[rr] = lsum[rr] * alpha[rr] + rsum;
        }
        #pragma unroll
        for (int nt = 0; nt < 4; nt++)
            #pragma unroll
            for (int rr = 0; rr < 4; rr++)
                o[nt][rr] *= alpha[rr];
        // P: C-layout -> LDS -> A-layout (m120 pattern)
        #pragma unroll
        for (int tc = 0; tc < 4; tc++)
            #pragma unroll
            for (int rr = 0; rr < 4; rr++)
                Ps[wave][quad * 4 + rr][tc * 16 + l15] = __float2bfloat16(s[tc][rr]);
        __syncthreads();
        short8 pa[2];
        #pragma unroll
        for (int ks = 0; ks < 2; ks++)
            pa[ks] = *(const short8*)&Ps[wave][l15][ks * 32 + quad * 8];
        #pragma unroll
        for (int ks = 0; ks < 2; ks++)
            #pragma unroll
            for (int nt = 0; nt < 4; nt++) {
                short8 vb = *(const short8*)&Vt[nt * 16 + l15][ks * 32 + quad * 8];
                o[nt] = __builtin_amdgcn_mfma_f32_16x16x32_bf16(pa[ks], vb, o[nt], 0, 0, 0);
            }
        __syncthreads();   // before next iteration overwrites Ks/Vt
    }

    // epilogue: normalize; write into q-columns of qkv (stride 3072)
    #pragma unroll
    for (int nt = 0; nt < 4; nt++)
        #pragma unroll
        for (int rr = 0; rr < 4; rr++) {
            float v = o[nt][rr] / lsum[rr];
            int row = b * 2048 + q0 + wave * 16 + quad * 4 + rr;
            int col = h * 64 + nt * 16 + l15;
            qkv[(size_t)row * rs + col] = __float2bfloat16(v);
        }
}

// ---------------------------------------------------------------------------
extern "C" void kernel_launch(void* const* d_in, const int* in_sizes, int n_in,
                              void* d_out, int out_size, void* d_ws, size_t ws_size,
                              hipStream_t stream)
{
    const float* x     = (const float*)d_in[0];  // [4,2048,1024] fp32
    const float* w_in  = (const float*)d_in[1];  // [3072,1024]   fp32
    const float* w_out = (const float*)d_in[2];  // [1024,1024]   fp32
    const float* b_out = (const float*)d_in[3];  // [1024]        fp32
    float* out = (float*)d_out;                  // [4,2048,1024] fp32

    // workspace layout (bf16): qkv 48MB | xb 16MB | wib 6MB | wob 2MB
    bf16* qkv = (bf16*)d_ws;                     // [8192, 3072]
    bf16* xb  = qkv + (size_t)8192 * 3072;       // [8192, 1024]
    bf16* wib = xb  + (size_t)8192 * 1024;       // [3072, 1024]
    bf16* wob = wib + (size_t)3072 * 1024;       // [1024, 1024]

    // 0) convert fp32 inputs to bf16
    cvt_f32_bf16<<<(8192 * 1024 / 4 + 255) / 256, 256, 0, stream>>>(x, xb, 8192 * 1024 / 4);
    cvt_f32_bf16<<<(3072 * 1024 / 4 + 255) / 256, 256, 0, stream>>>(w_in, wib, 3072 * 1024 / 4);
    cvt_f32_bf16<<<(1024 * 1024 / 4 + 255) / 256, 256, 0, stream>>>(w_out, wob, 1024 * 1024 / 4);

    // 1) qkv = x @ w_in^T
    gemm_bt<false, bf16><<<dim3(3072 / 128, 8192 / 128), 256, 0, stream>>>(
        xb, 1024, wib, nullptr, qkv, 8192, 3072, 1024);
    // 2) causal flash attention (writes attn output into q-columns of qkv)
    flash_attn<<<dim3(32, 16, 4), 256, 0, stream>>>(qkv);
    // 3) out = attn_out @ w_out^T + b_out  (A = q-columns of qkv, lda=3072)
    gemm_bt<true, float><<<dim3(1024 / 128, 8192 / 128), 256, 0, stream>>>(
        qkv, 3072, wob, b_out, out, 8192, 1024, 1024);
}

// Round 3
// 345.706 us; speedup vs baseline: 1.3088x; 1.3088x over previous
//
#include <hip/hip_runtime.h>
#include <hip/hip_bf16.h>
#include <cstdint>

typedef __hip_bfloat16 bf16;
typedef short short8 __attribute__((ext_vector_type(8)));
typedef float f32x4 __attribute__((ext_vector_type(4)));

#define AS1C(p) ((const __attribute__((address_space(1))) void*)(p))
#define AS3(p)  ((__attribute__((address_space(3))) void*)(p))

__device__ __forceinline__ float b2f(short s) {
    union { unsigned u; float f; } c; c.u = ((unsigned)(unsigned short)s) << 16; return c.f;
}

// DPP cross-lane (within 16-lane row). CTRL: 0xB1=quad xor1, 0x4E=quad xor2,
// 0x141=row_half_mirror (xor7 in 8), 0x140=row_mirror (xor15 in 16).
template<int CTRL>
__device__ __forceinline__ float dppf(float x) {
    return __int_as_float(__builtin_amdgcn_update_dpp(
        0, __float_as_int(x), CTRL, 0xF, 0xF, true));
}
__device__ __forceinline__ float row_max16(float x) {
    x = fmaxf(x, dppf<0xB1>(x));
    x = fmaxf(x, dppf<0x4E>(x));
    x = fmaxf(x, dppf<0x141>(x));
    x = fmaxf(x, dppf<0x140>(x));
    return x;
}
__device__ __forceinline__ float row_sum16(float x) {
    x += dppf<0xB1>(x);
    x += dppf<0x4E>(x);
    x += dppf<0x141>(x);
    x += dppf<0x140>(x);
    return x;
}

// ---------------------------------------------------------------------------
// fp32 -> bf16 conversion
// ---------------------------------------------------------------------------
__global__ void cvt_f32_bf16(const float* __restrict__ src, bf16* __restrict__ dst, int n4)
{
    int i = blockIdx.x * blockDim.x + threadIdx.x;
    if (i >= n4) return;
    float4 v = ((const float4*)src)[i];
    __align__(8) bf16 t[4] = { __float2bfloat16(v.x), __float2bfloat16(v.y),
                               __float2bfloat16(v.z), __float2bfloat16(v.w) };
    ((uint2*)dst)[i] = *(const uint2*)t;
}

// ---------------------------------------------------------------------------
// C[M,N] = A[M,K] @ B[N,K]^T (+ bias). m97 structure: 128x128 tile, BK=32,
// 4 waves 2x2, 16x16x32 bf16 MFMA, global_load_lds width=16.
// SPLIT_V: cols >= 2048 are written TRANSPOSED to vt[(b*16+h)*64+d][token]
// (for the QKV projection); cols < 2048 go to C with row stride ldc.
// ---------------------------------------------------------------------------
template<bool SPLIT_V, bool HAS_BIAS, typename OUT_T>
__global__ __launch_bounds__(256, 2)
void gemm_bt(const bf16* __restrict__ A, int lda, const bf16* __restrict__ B,
             const float* __restrict__ bias, OUT_T* __restrict__ C, int ldc,
             bf16* __restrict__ vt, int M, int N, int K)
{
    __shared__ __align__(16) bf16 As[128 * 32];
    __shared__ __align__(16) bf16 Bs[128 * 32];
    const int tid  = threadIdx.x;
    const int wave = tid >> 6, lane = tid & 63;
    const int wm = wave >> 1, wn = wave & 1;
    const int quad = lane >> 4, l15 = lane & 15;
    const int tile_m = blockIdx.y, tile_n = blockIdx.x;

    const bf16* Ap = A + (size_t)tile_m * 128 * lda;
    const bf16* Bp = B + (size_t)tile_n * 128 * K;

    const int srow = lane >> 2;
    const int scol = (lane & 3) * 8;

    f32x4 acc[4][4];
    #pragma unroll
    for (int i = 0; i < 4; i++)
        #pragma unroll
        for (int j = 0; j < 4; j++) acc[i][j] = (f32x4){0.f, 0.f, 0.f, 0.f};

    for (int k0 = 0; k0 < K; k0 += 32) {
        #pragma unroll
        for (int cc = 0; cc < 2; cc++) {
            int c = wave + cc * 4;
            const bf16* ga = Ap + (size_t)(c * 16 + srow) * lda + k0 + scol;
            __builtin_amdgcn_global_load_lds(AS1C(ga), AS3(&As[c * 16 * 32]), 16, 0, 0);
            const bf16* gb = Bp + (size_t)(c * 16 + srow) * K + k0 + scol;
            __builtin_amdgcn_global_load_lds(AS1C(gb), AS3(&Bs[c * 16 * 32]), 16, 0, 0);
        }
        __syncthreads();

        short8 af[4], bfr[4];
        #pragma unroll
        for (int mi = 0; mi < 4; mi++)
            af[mi] = *(const short8*)&As[(wm * 64 + mi * 16 + l15) * 32 + quad * 8];
        #pragma unroll
        for (int ni = 0; ni < 4; ni++)
            bfr[ni] = *(const short8*)&Bs[(wn * 64 + ni * 16 + l15) * 32 + quad * 8];
        #pragma unroll
        for (int mi = 0; mi < 4; mi++)
            #pragma unroll
            for (int ni = 0; ni < 4; ni++)
                acc[mi][ni] = __builtin_amdgcn_mfma_f32_16x16x32_bf16(
                    af[mi], bfr[ni], acc[mi][ni], 0, 0, 0);
        __syncthreads();
    }

    // epilogue: C/D layout row = quad*4+r, col = l15
    const bool vtile = SPLIT_V && (tile_n * 128 >= 2048);
    #pragma unroll
    for (int mi = 0; mi < 4; mi++) {
        #pragma unroll
        for (int ni = 0; ni < 4; ni++) {
            int coln = tile_n * 128 + wn * 64 + ni * 16 + l15;
            if (!vtile) {
                float bv = HAS_BIAS ? bias[coln] : 0.f;
                #pragma unroll
                for (int r = 0; r < 4; r++) {
                    int row = tile_m * 128 + wm * 64 + mi * 16 + quad * 4 + r;
                    float v = acc[mi][ni][r] + bv;
                    if constexpr (__is_same(OUT_T, float))
                        C[(size_t)row * ldc + coln] = v;
                    else
                        C[(size_t)row * ldc + coln] = __float2bfloat16(v);
                }
            } else {
                // V output, transposed: 4 consecutive tokens -> one 8B store
                int vcol = coln - 2048;                       // h*64 + d
                int row0 = tile_m * 128 + wm * 64 + mi * 16 + quad * 4;
                int bb = row0 >> 11, n0 = row0 & 2047;        // batch, token
                __align__(8) bf16 t4[4];
                #pragma unroll
                for (int r = 0; r < 4; r++) t4[r] = __float2bfloat16(acc[mi][ni][r]);
                *(uint2*)&vt[((size_t)(bb * 1024 + vcol)) * 2048 + n0] = *(const uint2*)t4;
            }
        }
    }
}

// ---------------------------------------------------------------------------
// Causal flash attention. qkv: [8192, 2048] bf16 = Q|K (each 1024 = 16h x 64),
// vt: [4*1024, 2048] = V transposed per (b,h): vt[(b*16+h)*64+d][token].
// One block per (q-tile 64, head, batch); 4 waves, wave w owns q rows w*16..+15.
// K/V register-prefetched; DPP softmax reductions; 2 barriers/iter.
// Output overwrites the Q columns of qkv.
// ---------------------------------------------------------------------------
__global__ __launch_bounds__(256, 2)
void flash_attn(bf16* __restrict__ qkv, const bf16* __restrict__ vt)
{
    const int qt = blockIdx.x;   // 0..31
    const int h  = blockIdx.y;   // 0..15
    const int b  = blockIdx.z;   // 0..3
    const int tid  = threadIdx.x;
    const int wave = tid >> 6, lane = tid & 63;
    const int quad = lane >> 4, l15 = lane & 15;

    __shared__ __align__(16) bf16 Qs[64][72];
    __shared__ __align__(16) bf16 Ks[64][72];
    __shared__ __align__(16) bf16 Vs[64][72];       // V^T tile: Vs[d][kc]
    __shared__ __align__(16) bf16 Ps[4][16][72];    // per-wave P tile

    const int r  = tid >> 2;         // staging row 0..63
    const int c0 = (tid & 3) * 16;   // staging col 0,16,32,48
    const int q0 = qt * 64;
    const size_t rs = 2048;

    // stage Q tile
    {
        const bf16* qg = qkv + (size_t)(b * 2048 + q0 + r) * rs + h * 64 + c0;
        *(uint4*)&Qs[r][c0]     = *(const uint4*)qg;
        *(uint4*)&Qs[r][c0 + 8] = *(const uint4*)(qg + 8);
    }
    __syncthreads();

    // A-frags for Q, with Hd^-1/2 = 2^-3 folded in (exact in bf16)
    short8 qa[2];
    #pragma unroll
    for (int ks = 0; ks < 2; ks++) {
        short8 t = *(const short8*)&Qs[wave * 16 + l15][ks * 32 + quad * 8];
        #pragma unroll
        for (int e = 0; e < 8; e++)
            t[e] = (short)__bfloat16_as_ushort(__float2bfloat16(b2f(t[e]) * 0.125f));
        qa[ks] = t;
    }

    f32x4 o[4];
    #pragma unroll
    for (int nt = 0; nt < 4; nt++) o[nt] = (f32x4){0.f, 0.f, 0.f, 0.f};
    float m_prev[4], lsum[4];
    #pragma unroll
    for (int rr = 0; rr < 4; rr++) { m_prev[rr] = -INFINITY; lsum[rr] = 0.f; }

    const bf16* kbase = qkv + (size_t)(b * 2048) * rs + 1024 + h * 64;   // + (j*64+r)*rs + c0
    const bf16* vbase = vt + ((size_t)(b * 16 + h) * 64) * 2048;         // + r*2048 + j*64 + c0

    // prefetch j=0
    uint4 kr0 = *(const uint4*)(kbase + (size_t)r * rs + c0);
    uint4 kr1 = *(const uint4*)(kbase + (size_t)r * rs + c0 + 8);
    uint4 vr0 = *(const uint4*)(vbase + (size_t)r * 2048 + c0);
    uint4 vr1 = *(const uint4*)(vbase + (size_t)r * 2048 + c0 + 8);

    for (int j = 0; j <= qt; j++) {
        *(uint4*)&Ks[r][c0]     = kr0;
        *(uint4*)&Ks[r][c0 + 8] = kr1;
        *(uint4*)&Vs[r][c0]     = vr0;
        *(uint4*)&Vs[r][c0 + 8] = vr1;
        __syncthreads();

        if (j < qt) {   // prefetch next tile (overlaps with compute below)
            kr0 = *(const uint4*)(kbase + (size_t)((j + 1) * 64 + r) * rs + c0);
            kr1 = *(const uint4*)(kbase + (size_t)((j + 1) * 64 + r) * rs + c0 + 8);
            vr0 = *(const uint4*)(vbase + (size_t)r * 2048 + (j + 1) * 64 + c0);
            vr1 = *(const uint4*)(vbase + (size_t)r * 2048 + (j + 1) * 64 + c0 + 8);
        }

        // S = Q K^T
        f32x4 s[4];
        #pragma unroll
        for (int tc = 0; tc < 4; tc++) {
            short8 kb0 = *(const short8*)&Ks[tc * 16 + l15][quad * 8];
            short8 kb1 = *(const short8*)&Ks[tc * 16 + l15][32 + quad * 8];
            f32x4 z = (f32x4){0.f, 0.f, 0.f, 0.f};
            z = __builtin_amdgcn_mfma_f32_16x16x32_bf16(qa[0], kb0, z, 0, 0, 0);
            z = __builtin_amdgcn_mfma_f32_16x16x32_bf16(qa[1], kb1, z, 0, 0, 0);
            s[tc] = z;
        }
        // causal mask (diagonal tile only; scale already folded into Q)
        if (j == qt) {
            #pragma unroll
            for (int tc = 0; tc < 4; tc++)
                #pragma unroll
                for (int rr = 0; rr < 4; rr++)
                    if ((tc * 16 + l15) > (wave * 16 + quad * 4 + rr))
                        s[tc][rr] = -INFINITY;
        }
        // online softmax, DPP row reductions (16-lane rows)
        float mnew[4], alpha[4];
        #pragma unroll
        for (int rr = 0; rr < 4; rr++) {
            float mr = fmaxf(fmaxf(s[0][rr], s[1][rr]), fmaxf(s[2][rr], s[3][rr]));
            mr = row_max16(mr);
            mnew[rr]  = fmaxf(m_prev[rr], mr);
            alpha[rr] = __expf(m_prev[rr] - mnew[rr]);
            m_prev[rr] = mnew[rr];
        }
        #pragma unroll
        for (int tc = 0; tc < 4; tc++)
            #pragma unroll
            for (int rr = 0; rr < 4; rr++)
                s[tc][rr] = __expf(s[tc][rr] - mnew[rr]);
        #pragma unroll
        for (int rr = 0; rr < 4; rr++) {
            float rsum = row_sum16(s[0][rr] + s[1][rr] + s[2][rr] + s[3][rr]);
            lsum[rr] = lsum[rr] * alpha[rr] + rsum;
        }
        #pragma unroll
        for (int nt = 0; nt < 4; nt++)
            #pragma unroll
            for (int rr = 0; rr < 4; rr++)
                o[nt][rr] *= alpha[rr];
        // P: C-layout -> LDS -> A-layout (wave-private region, no barrier)
        #pragma unroll
        for (int tc = 0; tc < 4; tc++)
            #pragma unroll
            for (int rr = 0; rr < 4; rr++)
                Ps[wave][quad * 4 + rr][tc * 16 + l15] = __float2bfloat16(s[tc][rr]);
        short8 pa[2];
        #pragma unroll
        for (int ks = 0; ks < 2; ks++)
            pa[ks] = *(const short8*)&Ps[wave][l15][ks * 32 + quad * 8];
        #pragma unroll
        for (int ks = 0; ks < 2; ks++)
            #pragma unroll
            for (int nt = 0; nt < 4; nt++) {
                short8 vb = *(const short8*)&Vs[nt * 16 + l15][ks * 32 + quad * 8];
                o[nt] = __builtin_amdgcn_mfma_f32_16x16x32_bf16(pa[ks], vb, o[nt], 0, 0, 0);
            }
        __syncthreads();   // before next iteration overwrites Ks/Vs
    }

    // epilogue: normalize; write into Q columns of qkv
    #pragma unroll
    for (int rr = 0; rr < 4; rr++) {
        float inv = 1.f / lsum[rr];
        int row = b * 2048 + q0 + wave * 16 + quad * 4 + rr;
        #pragma unroll
        for (int nt = 0; nt < 4; nt++) {
            int col = h * 64 + nt * 16 + l15;
            qkv[(size_t)row * rs + col] = __float2bfloat16(o[nt][rr] * inv);
        }
    }
}

// ---------------------------------------------------------------------------
extern "C" void kernel_launch(void* const* d_in, const int* in_sizes, int n_in,
                              void* d_out, int out_size, void* d_ws, size_t ws_size,
                              hipStream_t stream)
{
    const float* x     = (const float*)d_in[0];  // [4,2048,1024] fp32
    const float* w_in  = (const float*)d_in[1];  // [3072,1024]   fp32
    const float* w_out = (const float*)d_in[2];  // [1024,1024]   fp32
    const float* b_out = (const float*)d_in[3];  // [1024]        fp32
    float* out = (float*)d_out;                  // [4,2048,1024] fp32

    // ws: qkv(Q|K) 33.5MB | vt 16.8MB | xb 16.8MB | wib 6.3MB | wob 2.1MB
    bf16* qkv = (bf16*)d_ws;                     // [8192, 2048]
    bf16* vt  = qkv + (size_t)8192 * 2048;       // [4096, 2048]
    bf16* xb  = vt  + (size_t)4096 * 2048;       // [8192, 1024]
    bf16* wib = xb  + (size_t)8192 * 1024;       // [3072, 1024]
    bf16* wob = wib + (size_t)3072 * 1024;       // [1024, 1024]

    cvt_f32_bf16<<<(8192 * 1024 / 4 + 255) / 256, 256, 0, stream>>>(x, xb, 8192 * 1024 / 4);
    cvt_f32_bf16<<<(3072 * 1024 / 4 + 255) / 256, 256, 0, stream>>>(w_in, wib, 3072 * 1024 / 4);
    cvt_f32_bf16<<<(1024 * 1024 / 4 + 255) / 256, 256, 0, stream>>>(w_out, wob, 1024 * 1024 / 4);

    // 1) qkv = x @ w_in^T  (Q,K -> qkv stride 2048; V -> vt transposed)
    gemm_bt<true, false, bf16><<<dim3(3072 / 128, 8192 / 128), 256, 0, stream>>>(
        xb, 1024, wib, nullptr, qkv, 2048, vt, 8192, 3072, 1024);
    // 2) causal flash attention (output into Q columns of qkv)
    flash_attn<<<dim3(32, 16, 4), 256, 0, stream>>>(qkv, vt);
    // 3) out = attn_out @ w_out^T + b_out
    gemm_bt<false, true, float><<<dim3(1024 / 128, 8192 / 128), 256, 0, stream>>>(
        qkv, 2048, wob, b_out, out, 1024, nullptr, 8192, 1024, 1024);
}